// Round 2
// baseline (432.969 us; speedup 1.0000x reference)
//
#include <hip/hip_runtime.h>
#include <hip/hip_bf16.h>

typedef __attribute__((ext_vector_type(8))) __bf16 bf16x8;
typedef __attribute__((ext_vector_type(4))) __bf16 bf16x4;
typedef __attribute__((ext_vector_type(4))) float f32x4;

constexpr int B = 4, S = 2048, D = 1024, H = 16, DK = 64;

// ---------------------------------------------------------------------------
// Kernel 1: qkv = x @ w_qkv^T + b_qkv ; scatter to Q [B,H,S,DK] (scaled by
// 1/sqrt(DK)), K [B,H,S,DK], V^T [B,H,DK,S], all bf16.
// Tile 128x128, BK=32, 4 waves (2x2), each wave 64x64 via 4x4 16x16x32 MFMA.
// ---------------------------------------------------------------------------
__global__ __launch_bounds__(256) void qkv_gemm(const float* __restrict__ X,
                                                const float* __restrict__ W,
                                                const float* __restrict__ bias,
                                                __bf16* __restrict__ Qb,
                                                __bf16* __restrict__ Kb,
                                                __bf16* __restrict__ VTb) {
  __shared__ __bf16 As[128][40];  // +8 pad: stride 80B = 20 banks -> 2-way max
  __shared__ __bf16 Bs[128][40];
  const int tid = threadIdx.x;
  const int lane = tid & 63;
  const int wid = tid >> 6;
  const int wr = wid >> 1, wc = wid & 1;
  const int lr = lane & 15, lb = lane >> 4;
  const int m0 = blockIdx.x * 128, n0 = blockIdx.y * 128;
  const int srow = tid >> 3;        // 0..31
  const int scol = (tid & 7) << 2;  // 0,4,...,28

  f32x4 acc[4][4];
#pragma unroll
  for (int i = 0; i < 4; ++i)
#pragma unroll
    for (int j = 0; j < 4; ++j) acc[i][j] = f32x4{0.f, 0.f, 0.f, 0.f};

  for (int k0 = 0; k0 < D; k0 += 32) {
#pragma unroll
    for (int p = 0; p < 4; ++p) {
      const int r = p * 32 + srow;
      float4 a = *reinterpret_cast<const float4*>(&X[(size_t)(m0 + r) * D + k0 + scol]);
      float4 w = *reinterpret_cast<const float4*>(&W[(size_t)(n0 + r) * D + k0 + scol]);
      bf16x4 ab = {(__bf16)a.x, (__bf16)a.y, (__bf16)a.z, (__bf16)a.w};
      bf16x4 wb = {(__bf16)w.x, (__bf16)w.y, (__bf16)w.z, (__bf16)w.w};
      *reinterpret_cast<bf16x4*>(&As[r][scol]) = ab;
      *reinterpret_cast<bf16x4*>(&Bs[r][scol]) = wb;
    }
    __syncthreads();
    bf16x8 af[4], bfr[4];
#pragma unroll
    for (int m = 0; m < 4; ++m)
      af[m] = *reinterpret_cast<const bf16x8*>(&As[wr * 64 + m * 16 + lr][lb * 8]);
#pragma unroll
    for (int n = 0; n < 4; ++n)
      bfr[n] = *reinterpret_cast<const bf16x8*>(&Bs[wc * 64 + n * 16 + lr][lb * 8]);
#pragma unroll
    for (int m = 0; m < 4; ++m)
#pragma unroll
      for (int n = 0; n < 4; ++n)
        acc[m][n] = __builtin_amdgcn_mfma_f32_16x16x32_bf16(af[m], bfr[n], acc[m][n], 0, 0, 0);
    __syncthreads();
  }

  const int seg = n0 >> 10;  // 0:Q 1:K 2:V (block-uniform: 1024 % 128 == 0)
#pragma unroll
  for (int m = 0; m < 4; ++m)
#pragma unroll
    for (int n = 0; n < 4; ++n) {
      const int c = n0 + wc * 64 + n * 16 + lr;
      const int cc = c & 1023;
      const int h = cc >> 6, dk = cc & 63;
      const float bv = bias[c];
#pragma unroll
      for (int r = 0; r < 4; ++r) {
        const int t = m0 + wr * 64 + m * 16 + lb * 4 + r;
        const int bb = t >> 11;  // S = 2048
        const int s = t & 2047;
        const float v = acc[m][n][r] + bv;
        const size_t bh = (size_t)bb * H + h;
        if (seg == 0)
          Qb[(bh * S + s) * DK + dk] = (__bf16)(v * 0.125f);  // fold 1/sqrt(64)
        else if (seg == 1)
          Kb[(bh * S + s) * DK + dk] = (__bf16)v;
        else
          VTb[(bh * DK + dk) * S + s] = (__bf16)v;
      }
    }
}

// ---------------------------------------------------------------------------
// Kernel 2: causal flash attention. 1 wave per block, 32 q-rows per wave.
// KV tiles of 32. QK^T and PV via 16x16x32 bf16 MFMA; P transposed via
// padded LDS (wave-private, lgkmcnt-synced). K/V read from global (L2-fits).
// ---------------------------------------------------------------------------
__global__ __launch_bounds__(64) void attn_fwd(const __bf16* __restrict__ Qb,
                                               const __bf16* __restrict__ Kb,
                                               const __bf16* __restrict__ VTb,
                                               __bf16* __restrict__ AO) {
  __shared__ __bf16 Ps[32][40];
  const int lane = threadIdx.x;
  const int lr = lane & 15, lb = lane >> 4;
  const int q0 = blockIdx.x * 32;
  const int bh = blockIdx.y;
  const int bb = bh >> 4, h = bh & 15;
  const __bf16* Q = Qb + (size_t)bh * S * DK;
  const __bf16* K = Kb + (size_t)bh * S * DK;
  const __bf16* VT = VTb + (size_t)bh * DK * S;

  bf16x8 qf[2][2];
#pragma unroll
  for (int m = 0; m < 2; ++m)
#pragma unroll
    for (int d = 0; d < 2; ++d)
      qf[m][d] = *reinterpret_cast<const bf16x8*>(
          &Q[(size_t)(q0 + m * 16 + lr) * DK + d * 32 + lb * 8]);

  f32x4 o[2][4];
#pragma unroll
  for (int m = 0; m < 2; ++m)
#pragma unroll
    for (int n = 0; n < 4; ++n) o[m][n] = f32x4{0.f, 0.f, 0.f, 0.f};
  float mrun[2][4], lrun[2][4];
#pragma unroll
  for (int m = 0; m < 2; ++m)
#pragma unroll
    for (int r = 0; r < 4; ++r) {
      mrun[m][r] = -1e30f;
      lrun[m][r] = 0.f;
    }

  const int ntiles = blockIdx.x + 1;  // causal: kv0 <= q0
  for (int tile = 0; tile < ntiles; ++tile) {
    const int kv0 = tile * 32;
    bf16x8 kf[2][2];
#pragma unroll
    for (int kc = 0; kc < 2; ++kc)
#pragma unroll
      for (int d = 0; d < 2; ++d)
        kf[kc][d] = *reinterpret_cast<const bf16x8*>(
            &K[(size_t)(kv0 + kc * 16 + lr) * DK + d * 32 + lb * 8]);
    f32x4 sf[2][2];
#pragma unroll
    for (int m = 0; m < 2; ++m)
#pragma unroll
      for (int kc = 0; kc < 2; ++kc) {
        f32x4 z = f32x4{0.f, 0.f, 0.f, 0.f};
        z = __builtin_amdgcn_mfma_f32_16x16x32_bf16(qf[m][0], kf[kc][0], z, 0, 0, 0);
        z = __builtin_amdgcn_mfma_f32_16x16x32_bf16(qf[m][1], kf[kc][1], z, 0, 0, 0);
        sf[m][kc] = z;
      }
    if (tile == ntiles - 1) {  // diagonal tile: kv0 == q0, mask k > q
#pragma unroll
      for (int m = 0; m < 2; ++m)
#pragma unroll
        for (int kc = 0; kc < 2; ++kc)
#pragma unroll
          for (int r = 0; r < 4; ++r) {
            const int q = m * 16 + lb * 4 + r, k = kc * 16 + lr;
            if (k > q) sf[m][kc][r] = -1e30f;
          }
    }
    // online softmax (row = m*16 + 4*lb + r, cols spread over lr lanes)
#pragma unroll
    for (int m = 0; m < 2; ++m)
#pragma unroll
      for (int r = 0; r < 4; ++r) {
        float mx = fmaxf(sf[m][0][r], sf[m][1][r]);
#pragma unroll
        for (int off = 1; off < 16; off <<= 1) mx = fmaxf(mx, __shfl_xor(mx, off, 64));
        const float nm = fmaxf(mrun[m][r], mx);
        const float alpha = __expf(mrun[m][r] - nm);
        mrun[m][r] = nm;
        const float p0 = __expf(sf[m][0][r] - nm);
        const float p1 = __expf(sf[m][1][r] - nm);
        sf[m][0][r] = p0;
        sf[m][1][r] = p1;
        float rs = p0 + p1;
#pragma unroll
        for (int off = 1; off < 16; off <<= 1) rs += __shfl_xor(rs, off, 64);
        lrun[m][r] = lrun[m][r] * alpha + rs;
        // FIX (round 1): rescale ONLY row r's component, not the whole f32x4.
#pragma unroll
        for (int n = 0; n < 4; ++n) o[m][n][r] *= alpha;
      }
    // P -> LDS (C layout) then reread as A-fragments
#pragma unroll
    for (int m = 0; m < 2; ++m)
#pragma unroll
      for (int kc = 0; kc < 2; ++kc)
#pragma unroll
        for (int r = 0; r < 4; ++r)
          Ps[m * 16 + lb * 4 + r][kc * 16 + lr] = (__bf16)sf[m][kc][r];
    asm volatile("s_waitcnt lgkmcnt(0)" ::: "memory");
    __builtin_amdgcn_sched_barrier(0);
    bf16x8 pa[2];
#pragma unroll
    for (int m = 0; m < 2; ++m)
      pa[m] = *reinterpret_cast<const bf16x8*>(&Ps[m * 16 + lr][lb * 8]);
    bf16x8 vf[4];
#pragma unroll
    for (int n = 0; n < 4; ++n)
      vf[n] = *reinterpret_cast<const bf16x8*>(&VT[(size_t)(n * 16 + lr) * S + kv0 + lb * 8]);
#pragma unroll
    for (int m = 0; m < 2; ++m)
#pragma unroll
      for (int n = 0; n < 4; ++n)
        o[m][n] = __builtin_amdgcn_mfma_f32_16x16x32_bf16(pa[m], vf[n], o[m][n], 0, 0, 0);
  }
  // epilogue: normalize and write merged-head bf16 [B,S,D]
#pragma unroll
  for (int m = 0; m < 2; ++m)
#pragma unroll
    for (int n = 0; n < 4; ++n)
#pragma unroll
      for (int r = 0; r < 4; ++r) {
        const int q = q0 + m * 16 + lb * 4 + r;
        const float v = o[m][n][r] / lrun[m][r];
        AO[((size_t)(bb * S + q)) * D + h * DK + n * 16 + lr] = (__bf16)v;
      }
}

// ---------------------------------------------------------------------------
// Kernel 3: out = attn_out @ w_o^T, f32 output. Same tile structure as k1;
// A is already bf16, W converted during staging.
// ---------------------------------------------------------------------------
__global__ __launch_bounds__(256) void out_gemm(const __bf16* __restrict__ AOp,
                                                const float* __restrict__ W,
                                                float* __restrict__ Out) {
  __shared__ __bf16 As[128][40];
  __shared__ __bf16 Bs[128][40];
  const int tid = threadIdx.x;
  const int lane = tid & 63;
  const int wid = tid >> 6;
  const int wr = wid >> 1, wc = wid & 1;
  const int lr = lane & 15, lb = lane >> 4;
  const int m0 = blockIdx.x * 128, n0 = blockIdx.y * 128;
  const int srow = tid >> 3, scol = (tid & 7) << 2;  // W staging (f32x4)
  const int arow = tid >> 2, acol = (tid & 3) << 3;  // A staging (bf16x8)

  f32x4 acc[4][4];
#pragma unroll
  for (int i = 0; i < 4; ++i)
#pragma unroll
    for (int j = 0; j < 4; ++j) acc[i][j] = f32x4{0.f, 0.f, 0.f, 0.f};

  for (int k0 = 0; k0 < D; k0 += 32) {
#pragma unroll
    for (int p = 0; p < 2; ++p) {
      const int r = p * 64 + arow;
      bf16x8 av = *reinterpret_cast<const bf16x8*>(&AOp[(size_t)(m0 + r) * D + k0 + acol]);
      *reinterpret_cast<bf16x8*>(&As[r][acol]) = av;
    }
#pragma unroll
    for (int p = 0; p < 4; ++p) {
      const int r = p * 32 + srow;
      float4 w = *reinterpret_cast<const float4*>(&W[(size_t)(n0 + r) * D + k0 + scol]);
      bf16x4 wb = {(__bf16)w.x, (__bf16)w.y, (__bf16)w.z, (__bf16)w.w};
      *reinterpret_cast<bf16x4*>(&Bs[r][scol]) = wb;
    }
    __syncthreads();
    bf16x8 af[4], bfr[4];
#pragma unroll
    for (int m = 0; m < 4; ++m)
      af[m] = *reinterpret_cast<const bf16x8*>(&As[wr * 64 + m * 16 + lr][lb * 8]);
#pragma unroll
    for (int n = 0; n < 4; ++n)
      bfr[n] = *reinterpret_cast<const bf16x8*>(&Bs[wc * 64 + n * 16 + lr][lb * 8]);
#pragma unroll
    for (int m = 0; m < 4; ++m)
#pragma unroll
      for (int n = 0; n < 4; ++n)
        acc[m][n] = __builtin_amdgcn_mfma_f32_16x16x32_bf16(af[m], bfr[n], acc[m][n], 0, 0, 0);
    __syncthreads();
  }

#pragma unroll
  for (int m = 0; m < 4; ++m)
#pragma unroll
    for (int n = 0; n < 4; ++n)
#pragma unroll
      for (int r = 0; r < 4; ++r)
        Out[(size_t)(m0 + wr * 64 + m * 16 + lb * 4 + r) * D + n0 + wc * 64 + n * 16 + lr] =
            acc[m][n][r];
}

// ---------------------------------------------------------------------------
extern "C" void kernel_launch(void* const* d_in, const int* in_sizes, int n_in,
                              void* d_out, int out_size, void* d_ws, size_t ws_size,
                              hipStream_t stream) {
  (void)in_sizes; (void)n_in; (void)out_size; (void)ws_size;
  const float* x = (const float*)d_in[0];
  // d_in[1] = causal mask — recomputed analytically, not read
  const float* w_qkv = (const float*)d_in[2];
  const float* b_qkv = (const float*)d_in[3];
  const float* w_o = (const float*)d_in[4];
  float* out = (float*)d_out;

  const size_t qkv_elems = (size_t)B * H * S * DK;  // 8,388,608
  __bf16* Qb = (__bf16*)d_ws;
  __bf16* Kb = Qb + qkv_elems;
  __bf16* VTb = Kb + qkv_elems;
  __bf16* AO = VTb + qkv_elems;  // total 64 MB of workspace

  qkv_gemm<<<dim3(64, 24), 256, 0, stream>>>(x, w_qkv, b_qkv, Qb, Kb, VTb);
  attn_fwd<<<dim3(S / 32, B * H), 64, 0, stream>>>(Qb, Kb, VTb, AO);
  out_gemm<<<dim3(64, 8), 256, 0, stream>>>(AO, w_o, out);
}

// Round 3
// 381.911 us; speedup vs baseline: 1.1337x; 1.1337x over previous
//
#include <hip/hip_runtime.h>
#include <hip/hip_bf16.h>

typedef __attribute__((ext_vector_type(8))) __bf16 bf16x8;
typedef __attribute__((ext_vector_type(4))) __bf16 bf16x4;
typedef __attribute__((ext_vector_type(4))) float f32x4;

constexpr int B = 4, S = 2048, D = 1024, H = 16, DK = 64;

// ---------------------------------------------------------------------------
// Kernel 1: qkv = x @ w_qkv^T + b_qkv ; scatter to Q [B,H,S,DK] (scaled by
// 1/sqrt(DK)), K [B,H,S,DK], V^T [B,H,DK,S], all bf16.
// ---------------------------------------------------------------------------
__global__ __launch_bounds__(256) void qkv_gemm(const float* __restrict__ X,
                                                const float* __restrict__ W,
                                                const float* __restrict__ bias,
                                                __bf16* __restrict__ Qb,
                                                __bf16* __restrict__ Kb,
                                                __bf16* __restrict__ VTb) {
  __shared__ __bf16 As[128][40];
  __shared__ __bf16 Bs[128][40];
  const int tid = threadIdx.x;
  const int lane = tid & 63;
  const int wid = tid >> 6;
  const int wr = wid >> 1, wc = wid & 1;
  const int lr = lane & 15, lb = lane >> 4;
  const int m0 = blockIdx.x * 128, n0 = blockIdx.y * 128;
  const int srow = tid >> 3;
  const int scol = (tid & 7) << 2;

  f32x4 acc[4][4];
#pragma unroll
  for (int i = 0; i < 4; ++i)
#pragma unroll
    for (int j = 0; j < 4; ++j) acc[i][j] = f32x4{0.f, 0.f, 0.f, 0.f};

  for (int k0 = 0; k0 < D; k0 += 32) {
#pragma unroll
    for (int p = 0; p < 4; ++p) {
      const int r = p * 32 + srow;
      float4 a = *reinterpret_cast<const float4*>(&X[(size_t)(m0 + r) * D + k0 + scol]);
      float4 w = *reinterpret_cast<const float4*>(&W[(size_t)(n0 + r) * D + k0 + scol]);
      bf16x4 ab = {(__bf16)a.x, (__bf16)a.y, (__bf16)a.z, (__bf16)a.w};
      bf16x4 wb = {(__bf16)w.x, (__bf16)w.y, (__bf16)w.z, (__bf16)w.w};
      *reinterpret_cast<bf16x4*>(&As[r][scol]) = ab;
      *reinterpret_cast<bf16x4*>(&Bs[r][scol]) = wb;
    }
    __syncthreads();
    bf16x8 af[4], bfr[4];
#pragma unroll
    for (int m = 0; m < 4; ++m)
      af[m] = *reinterpret_cast<const bf16x8*>(&As[wr * 64 + m * 16 + lr][lb * 8]);
#pragma unroll
    for (int n = 0; n < 4; ++n)
      bfr[n] = *reinterpret_cast<const bf16x8*>(&Bs[wc * 64 + n * 16 + lr][lb * 8]);
#pragma unroll
    for (int m = 0; m < 4; ++m)
#pragma unroll
      for (int n = 0; n < 4; ++n)
        acc[m][n] = __builtin_amdgcn_mfma_f32_16x16x32_bf16(af[m], bfr[n], acc[m][n], 0, 0, 0);
    __syncthreads();
  }

  const int seg = n0 >> 10;
#pragma unroll
  for (int m = 0; m < 4; ++m)
#pragma unroll
    for (int n = 0; n < 4; ++n) {
      const int c = n0 + wc * 64 + n * 16 + lr;
      const int cc = c & 1023;
      const int h = cc >> 6, dk = cc & 63;
      const float bv = bias[c];
#pragma unroll
      for (int r = 0; r < 4; ++r) {
        const int t = m0 + wr * 64 + m * 16 + lb * 4 + r;
        const int bb = t >> 11;
        const int s = t & 2047;
        const float v = acc[m][n][r] + bv;
        const size_t bh = (size_t)bb * H + h;
        if (seg == 0)
          Qb[(bh * S + s) * DK + dk] = (__bf16)(v * 0.125f);
        else if (seg == 1)
          Kb[(bh * S + s) * DK + dk] = (__bf16)v;
        else
          VTb[(bh * DK + dk) * S + s] = (__bf16)v;
      }
    }
}

// ---------------------------------------------------------------------------
// Kernel 2 (round 2 rewrite): causal flash attention.
// 4 waves/block (256 thr), wave w owns q-tile [q0, q0+32), q0 = xb*128 + w*32.
// KVBLK=64. LPT: xb reversed so heaviest blocks launch first.
// Pipeline: V loads issued at top (hide under QK+softmax); K register
// double-buffer (next tile issued before softmax, used next iter).
// ---------------------------------------------------------------------------
__global__ __launch_bounds__(256) void attn_fwd(const __bf16* __restrict__ Qb,
                                                const __bf16* __restrict__ Kb,
                                                const __bf16* __restrict__ VTb,
                                                __bf16* __restrict__ AO) {
  __shared__ __bf16 Ps[4][32][72];  // per-wave P buffer, +8 pad
  const int tid = threadIdx.x;
  const int lane = tid & 63;
  const int w = tid >> 6;
  const int lr = lane & 15, lb = lane >> 4;
  const int xb = (int)gridDim.x - 1 - (int)blockIdx.x;  // LPT order
  const int q0 = xb * 128 + w * 32;
  const int bh = blockIdx.y;
  const int bb = bh >> 4, h = bh & 15;
  const __bf16* Q = Qb + (size_t)bh * S * DK;
  const __bf16* K = Kb + (size_t)bh * S * DK;
  const __bf16* VT = VTb + (size_t)bh * DK * S;

  bf16x8 qf[2][2];
#pragma unroll
  for (int m = 0; m < 2; ++m)
#pragma unroll
    for (int d = 0; d < 2; ++d)
      qf[m][d] = *reinterpret_cast<const bf16x8*>(
          &Q[(size_t)(q0 + m * 16 + lr) * DK + d * 32 + lb * 8]);

  f32x4 o[2][4];
#pragma unroll
  for (int m = 0; m < 2; ++m)
#pragma unroll
    for (int n = 0; n < 4; ++n) o[m][n] = f32x4{0.f, 0.f, 0.f, 0.f};
  float mrun[2][4], lrun[2][4];
#pragma unroll
  for (int m = 0; m < 2; ++m)
#pragma unroll
    for (int r = 0; r < 4; ++r) {
      mrun[m][r] = -1e30f;
      lrun[m][r] = 0.f;
    }

  const int ntiles = q0 / 64 + 1;  // covers kv up to q0+31 (q0 % 64 in {0,32})

  bf16x8 kfA[4][2], kfB[4][2];
#pragma unroll
  for (int kc = 0; kc < 4; ++kc)
#pragma unroll
    for (int d = 0; d < 2; ++d)
      kfA[kc][d] = *reinterpret_cast<const bf16x8*>(
          &K[(size_t)(kc * 16 + lr) * DK + d * 32 + lb * 8]);

  for (int t = 0; t < ntiles; ++t) {
    const int kv0 = t * 64;
    // V loads for this tile, issued early (consumed at PV below)
    bf16x8 vf[4][2];
#pragma unroll
    for (int n = 0; n < 4; ++n)
#pragma unroll
      for (int ks = 0; ks < 2; ++ks)
        vf[n][ks] = *reinterpret_cast<const bf16x8*>(
            &VT[(size_t)(n * 16 + lr) * S + kv0 + ks * 32 + lb * 8]);

    // QK^T: S-tile [32 q rows] x [64 kv cols]
    f32x4 sf[2][4];
#pragma unroll
    for (int m = 0; m < 2; ++m)
#pragma unroll
      for (int kc = 0; kc < 4; ++kc) {
        f32x4 z = f32x4{0.f, 0.f, 0.f, 0.f};
        z = __builtin_amdgcn_mfma_f32_16x16x32_bf16(qf[m][0], kfA[kc][0], z, 0, 0, 0);
        z = __builtin_amdgcn_mfma_f32_16x16x32_bf16(qf[m][1], kfA[kc][1], z, 0, 0, 0);
        sf[m][kc] = z;
      }

    // prefetch next K tile (register double-buffer)
    if (t + 1 < ntiles) {
      const int nk0 = (t + 1) * 64;
#pragma unroll
      for (int kc = 0; kc < 4; ++kc)
#pragma unroll
        for (int d = 0; d < 2; ++d)
          kfB[kc][d] = *reinterpret_cast<const bf16x8*>(
              &K[(size_t)(nk0 + kc * 16 + lr) * DK + d * 32 + lb * 8]);
    }

    if (t == ntiles - 1) {  // diagonal tile: mask kv0+kloc > q0+qloc
#pragma unroll
      for (int m = 0; m < 2; ++m)
#pragma unroll
        for (int kc = 0; kc < 4; ++kc)
#pragma unroll
          for (int r = 0; r < 4; ++r) {
            const int qg = q0 + m * 16 + lb * 4 + r;
            const int kg = kv0 + kc * 16 + lr;
            if (kg > qg) sf[m][kc][r] = -1e30f;
          }
    }

    // online softmax; row = m*16 + 4*lb + r, cols over {kc, lr}
#pragma unroll
    for (int m = 0; m < 2; ++m)
#pragma unroll
      for (int r = 0; r < 4; ++r) {
        float mx = fmaxf(fmaxf(sf[m][0][r], sf[m][1][r]), fmaxf(sf[m][2][r], sf[m][3][r]));
#pragma unroll
        for (int off = 1; off < 16; off <<= 1) mx = fmaxf(mx, __shfl_xor(mx, off, 64));
        const float nm = fmaxf(mrun[m][r], mx);
        const float alpha = __expf(mrun[m][r] - nm);
        mrun[m][r] = nm;
        float rs = 0.f;
#pragma unroll
        for (int kc = 0; kc < 4; ++kc) {
          const float p = __expf(sf[m][kc][r] - nm);
          sf[m][kc][r] = p;
          rs += p;
        }
#pragma unroll
        for (int off = 1; off < 16; off <<= 1) rs += __shfl_xor(rs, off, 64);
        lrun[m][r] = lrun[m][r] * alpha + rs;
#pragma unroll
        for (int n = 0; n < 4; ++n) o[m][n][r] *= alpha;
      }

    // P -> LDS (C layout) then reread as PV A-fragments
#pragma unroll
    for (int m = 0; m < 2; ++m)
#pragma unroll
      for (int kc = 0; kc < 4; ++kc)
#pragma unroll
        for (int r = 0; r < 4; ++r)
          Ps[w][m * 16 + lb * 4 + r][kc * 16 + lr] = (__bf16)sf[m][kc][r];
    asm volatile("s_waitcnt lgkmcnt(0)" ::: "memory");
    __builtin_amdgcn_sched_barrier(0);
    bf16x8 pa[2][2];
#pragma unroll
    for (int m = 0; m < 2; ++m)
#pragma unroll
      for (int ks = 0; ks < 2; ++ks)
        pa[m][ks] = *reinterpret_cast<const bf16x8*>(&Ps[w][m * 16 + lr][ks * 32 + lb * 8]);

#pragma unroll
    for (int m = 0; m < 2; ++m)
#pragma unroll
      for (int n = 0; n < 4; ++n) {
        o[m][n] = __builtin_amdgcn_mfma_f32_16x16x32_bf16(pa[m][0], vf[n][0], o[m][n], 0, 0, 0);
        o[m][n] = __builtin_amdgcn_mfma_f32_16x16x32_bf16(pa[m][1], vf[n][1], o[m][n], 0, 0, 0);
      }

    // rotate K double-buffer
#pragma unroll
    for (int kc = 0; kc < 4; ++kc)
#pragma unroll
      for (int d = 0; d < 2; ++d) kfA[kc][d] = kfB[kc][d];
  }

  // epilogue: normalize, write merged-head bf16 [B,S,D]
#pragma unroll
  for (int m = 0; m < 2; ++m)
#pragma unroll
    for (int n = 0; n < 4; ++n)
#pragma unroll
      for (int r = 0; r < 4; ++r) {
        const int q = q0 + m * 16 + lb * 4 + r;
        const float v = o[m][n][r] / lrun[m][r];
        AO[((size_t)(bb * S + q)) * D + h * DK + n * 16 + lr] = (__bf16)v;
      }
}

// ---------------------------------------------------------------------------
// Kernel 3: out = attn_out @ w_o^T, f32 output.
// ---------------------------------------------------------------------------
__global__ __launch_bounds__(256) void out_gemm(const __bf16* __restrict__ AOp,
                                                const float* __restrict__ W,
                                                float* __restrict__ Out) {
  __shared__ __bf16 As[128][40];
  __shared__ __bf16 Bs[128][40];
  const int tid = threadIdx.x;
  const int lane = tid & 63;
  const int wid = tid >> 6;
  const int wr = wid >> 1, wc = wid & 1;
  const int lr = lane & 15, lb = lane >> 4;
  const int m0 = blockIdx.x * 128, n0 = blockIdx.y * 128;
  const int srow = tid >> 3, scol = (tid & 7) << 2;
  const int arow = tid >> 2, acol = (tid & 3) << 3;

  f32x4 acc[4][4];
#pragma unroll
  for (int i = 0; i < 4; ++i)
#pragma unroll
    for (int j = 0; j < 4; ++j) acc[i][j] = f32x4{0.f, 0.f, 0.f, 0.f};

  for (int k0 = 0; k0 < D; k0 += 32) {
#pragma unroll
    for (int p = 0; p < 2; ++p) {
      const int r = p * 64 + arow;
      bf16x8 av = *reinterpret_cast<const bf16x8*>(&AOp[(size_t)(m0 + r) * D + k0 + acol]);
      *reinterpret_cast<bf16x8*>(&As[r][acol]) = av;
    }
#pragma unroll
    for (int p = 0; p < 4; ++p) {
      const int r = p * 32 + srow;
      float4 w = *reinterpret_cast<const float4*>(&W[(size_t)(n0 + r) * D + k0 + scol]);
      bf16x4 wb = {(__bf16)w.x, (__bf16)w.y, (__bf16)w.z, (__bf16)w.w};
      *reinterpret_cast<bf16x4*>(&Bs[r][scol]) = wb;
    }
    __syncthreads();
    bf16x8 af[4], bfr[4];
#pragma unroll
    for (int m = 0; m < 4; ++m)
      af[m] = *reinterpret_cast<const bf16x8*>(&As[wr * 64 + m * 16 + lr][lb * 8]);
#pragma unroll
    for (int n = 0; n < 4; ++n)
      bfr[n] = *reinterpret_cast<const bf16x8*>(&Bs[wc * 64 + n * 16 + lr][lb * 8]);
#pragma unroll
    for (int m = 0; m < 4; ++m)
#pragma unroll
      for (int n = 0; n < 4; ++n)
        acc[m][n] = __builtin_amdgcn_mfma_f32_16x16x32_bf16(af[m], bfr[n], acc[m][n], 0, 0, 0);
    __syncthreads();
  }

#pragma unroll
  for (int m = 0; m < 4; ++m)
#pragma unroll
    for (int n = 0; n < 4; ++n)
#pragma unroll
      for (int r = 0; r < 4; ++r)
        Out[(size_t)(m0 + wr * 64 + m * 16 + lb * 4 + r) * D + n0 + wc * 64 + n * 16 + lr] =
            acc[m][n][r];
}

// ---------------------------------------------------------------------------
extern "C" void kernel_launch(void* const* d_in, const int* in_sizes, int n_in,
                              void* d_out, int out_size, void* d_ws, size_t ws_size,
                              hipStream_t stream) {
  (void)in_sizes; (void)n_in; (void)out_size; (void)ws_size;
  const float* x = (const float*)d_in[0];
  // d_in[1] = causal mask — recomputed analytically, not read
  const float* w_qkv = (const float*)d_in[2];
  const float* b_qkv = (const float*)d_in[3];
  const float* w_o = (const float*)d_in[4];
  float* out = (float*)d_out;

  const size_t qkv_elems = (size_t)B * H * S * DK;  // 8,388,608
  __bf16* Qb = (__bf16*)d_ws;
  __bf16* Kb = Qb + qkv_elems;
  __bf16* VTb = Kb + qkv_elems;
  __bf16* AO = VTb + qkv_elems;  // 64 MB of workspace

  qkv_gemm<<<dim3(64, 24), 256, 0, stream>>>(x, w_qkv, b_qkv, Qb, Kb, VTb);
  attn_fwd<<<dim3(S / 128, B * H), 256, 0, stream>>>(Qb, Kb, VTb, AO);
  out_gemm<<<dim3(64, 8), 256, 0, stream>>>(AO, w_o, out);
}

// Round 4
// 340.866 us; speedup vs baseline: 1.2702x; 1.1204x over previous
//
#include <hip/hip_runtime.h>
#include <hip/hip_bf16.h>

typedef __attribute__((ext_vector_type(8))) __bf16 bf16x8;
typedef __attribute__((ext_vector_type(4))) __bf16 bf16x4;
typedef __attribute__((ext_vector_type(4))) float f32x4;

constexpr int B = 4, S = 2048, D = 1024, H = 16, DK = 64;

// ---------------------------------------------------------------------------
// Kernel 1: qkv = x @ w_qkv^T + b_qkv ; scatter to Q [B,H,S,DK] (scaled by
// 1/sqrt(DK)), K [B,H,S,DK], V^T [B,H,DK,S], all bf16.
// ---------------------------------------------------------------------------
__global__ __launch_bounds__(256) void qkv_gemm(const float* __restrict__ X,
                                                const float* __restrict__ W,
                                                const float* __restrict__ bias,
                                                __bf16* __restrict__ Qb,
                                                __bf16* __restrict__ Kb,
                                                __bf16* __restrict__ VTb) {
  __shared__ __bf16 As[128][40];
  __shared__ __bf16 Bs[128][40];
  const int tid = threadIdx.x;
  const int lane = tid & 63;
  const int wid = tid >> 6;
  const int wr = wid >> 1, wc = wid & 1;
  const int lr = lane & 15, lb = lane >> 4;
  const int m0 = blockIdx.x * 128, n0 = blockIdx.y * 128;
  const int srow = tid >> 3;
  const int scol = (tid & 7) << 2;

  f32x4 acc[4][4];
#pragma unroll
  for (int i = 0; i < 4; ++i)
#pragma unroll
    for (int j = 0; j < 4; ++j) acc[i][j] = f32x4{0.f, 0.f, 0.f, 0.f};

  for (int k0 = 0; k0 < D; k0 += 32) {
#pragma unroll
    for (int p = 0; p < 4; ++p) {
      const int r = p * 32 + srow;
      float4 a = *reinterpret_cast<const float4*>(&X[(size_t)(m0 + r) * D + k0 + scol]);
      float4 w = *reinterpret_cast<const float4*>(&W[(size_t)(n0 + r) * D + k0 + scol]);
      bf16x4 ab = {(__bf16)a.x, (__bf16)a.y, (__bf16)a.z, (__bf16)a.w};
      bf16x4 wb = {(__bf16)w.x, (__bf16)w.y, (__bf16)w.z, (__bf16)w.w};
      *reinterpret_cast<bf16x4*>(&As[r][scol]) = ab;
      *reinterpret_cast<bf16x4*>(&Bs[r][scol]) = wb;
    }
    __syncthreads();
    bf16x8 af[4], bfr[4];
#pragma unroll
    for (int m = 0; m < 4; ++m)
      af[m] = *reinterpret_cast<const bf16x8*>(&As[wr * 64 + m * 16 + lr][lb * 8]);
#pragma unroll
    for (int n = 0; n < 4; ++n)
      bfr[n] = *reinterpret_cast<const bf16x8*>(&Bs[wc * 64 + n * 16 + lr][lb * 8]);
#pragma unroll
    for (int m = 0; m < 4; ++m)
#pragma unroll
      for (int n = 0; n < 4; ++n)
        acc[m][n] = __builtin_amdgcn_mfma_f32_16x16x32_bf16(af[m], bfr[n], acc[m][n], 0, 0, 0);
    __syncthreads();
  }

  const int seg = n0 >> 10;
#pragma unroll
  for (int m = 0; m < 4; ++m)
#pragma unroll
    for (int n = 0; n < 4; ++n) {
      const int c = n0 + wc * 64 + n * 16 + lr;
      const int cc = c & 1023;
      const int h = cc >> 6, dk = cc & 63;
      const float bv = bias[c];
#pragma unroll
      for (int r = 0; r < 4; ++r) {
        const int t = m0 + wr * 64 + m * 16 + lb * 4 + r;
        const int bb = t >> 11;
        const int s = t & 2047;
        const float v = acc[m][n][r] + bv;
        const size_t bh = (size_t)bb * H + h;
        if (seg == 0)
          Qb[(bh * S + s) * DK + dk] = (__bf16)(v * 0.125f);
        else if (seg == 1)
          Kb[(bh * S + s) * DK + dk] = (__bf16)v;
        else
          VTb[(bh * DK + dk) * S + s] = (__bf16)v;
      }
    }
}

// ---------------------------------------------------------------------------
// Kernel 2 (round 3 rewrite): causal flash attention, swapped-QK^T softmax.
// Flat grid 1024; decode: xcd = flat&7, idx = flat>>3, bh = (idx>>4)*8 + xcd
// (all q-tiles of a head on one XCD under round-robin dispatch; 8 heads/XCD
// = 4MB K/V = L2-sized), qt = 15-(idx&15) (LPT heavy-first).
// 4 waves/block, wave owns 32 q-rows; KVBLK=64.
// QK^T computed swapped: st = mfma(K,Q) -> S^T, so softmax is 15 in-lane
// fmax + 2 shfl_xor per subtile (vs 4-step chains), P written as b64.
// Defer-max (THR=8) skips rescale when running max doesn't grow.
// ---------------------------------------------------------------------------
__global__ __launch_bounds__(256) void attn_fwd(const __bf16* __restrict__ Qb,
                                                const __bf16* __restrict__ Kb,
                                                const __bf16* __restrict__ VTb,
                                                __bf16* __restrict__ AO) {
  __shared__ __bf16 Ps[4][32][72];
  const int tid = threadIdx.x;
  const int lane = tid & 63;
  const int w = tid >> 6;
  const int lr = lane & 15, lb = lane >> 4;

  const int flat = blockIdx.x;
  const int xcd = flat & 7;
  const int idx = flat >> 3;
  const int bh = (idx >> 4) * 8 + xcd;
  const int qt = 15 - (idx & 15);
  const int q0 = qt * 128 + w * 32;
  const int bb = bh >> 4, h = bh & 15;

  const __bf16* Q = Qb + (size_t)bh * S * DK;
  const __bf16* K = Kb + (size_t)bh * S * DK;
  const __bf16* VT = VTb + (size_t)bh * DK * S;

  bf16x8 qf[2][2];
#pragma unroll
  for (int m = 0; m < 2; ++m)
#pragma unroll
    for (int d = 0; d < 2; ++d)
      qf[m][d] = *reinterpret_cast<const bf16x8*>(
          &Q[(size_t)(q0 + m * 16 + lr) * DK + d * 32 + lb * 8]);

  f32x4 o[2][4];
#pragma unroll
  for (int m = 0; m < 2; ++m)
#pragma unroll
    for (int n = 0; n < 4; ++n) o[m][n] = f32x4{0.f, 0.f, 0.f, 0.f};
  float mrun[2], lrun[2];  // per q = lr (softmax layout)
#pragma unroll
  for (int m = 0; m < 2; ++m) {
    mrun[m] = -1e30f;
    lrun[m] = 0.f;
  }

  const int ntiles = q0 / 64 + 1;

  for (int t = 0; t < ntiles; ++t) {
    const int kv0 = t * 64;
    // K fragments (consumed immediately by QK^T)
    bf16x8 kf[4][2];
#pragma unroll
    for (int kc = 0; kc < 4; ++kc)
#pragma unroll
      for (int d = 0; d < 2; ++d)
        kf[kc][d] = *reinterpret_cast<const bf16x8*>(
            &K[(size_t)(kv0 + kc * 16 + lr) * DK + d * 32 + lb * 8]);
    // V fragments issued early, consumed at PV (latency hidden under softmax)
    bf16x8 vf[4][2];
#pragma unroll
    for (int n = 0; n < 4; ++n)
#pragma unroll
      for (int ks = 0; ks < 2; ++ks)
        vf[n][ks] = *reinterpret_cast<const bf16x8*>(
            &VT[(size_t)(n * 16 + lr) * S + kv0 + ks * 32 + lb * 8]);

    // swapped QK^T: st[m][kc][r] = S^T[k = kv0+kc*16+4lb+r][q = q0+m*16+lr]
    f32x4 st[2][4];
    __builtin_amdgcn_s_setprio(1);
#pragma unroll
    for (int m = 0; m < 2; ++m)
#pragma unroll
      for (int kc = 0; kc < 4; ++kc) {
        f32x4 z = f32x4{0.f, 0.f, 0.f, 0.f};
        z = __builtin_amdgcn_mfma_f32_16x16x32_bf16(kf[kc][0], qf[m][0], z, 0, 0, 0);
        z = __builtin_amdgcn_mfma_f32_16x16x32_bf16(kf[kc][1], qf[m][1], z, 0, 0, 0);
        st[m][kc] = z;
      }
    __builtin_amdgcn_s_setprio(0);

    if (t == ntiles - 1) {  // diagonal tile: mask k > q
#pragma unroll
      for (int m = 0; m < 2; ++m) {
        const int qg = q0 + m * 16 + lr;
#pragma unroll
        for (int kc = 0; kc < 4; ++kc)
#pragma unroll
          for (int r = 0; r < 4; ++r) {
            const int kg = kv0 + kc * 16 + 4 * lb + r;
            if (kg > qg) st[m][kc][r] = -1e30f;
          }
      }
    }

#pragma unroll
    for (int m = 0; m < 2; ++m) {
      // column max over all 64 k: in-lane 16 then across lb quarters
      float mx = st[m][0][0];
#pragma unroll
      for (int kc = 0; kc < 4; ++kc)
#pragma unroll
        for (int r = 0; r < 4; ++r) mx = fmaxf(mx, st[m][kc][r]);
      mx = fmaxf(mx, __shfl_xor(mx, 16, 64));
      mx = fmaxf(mx, __shfl_xor(mx, 32, 64));

      const bool grow = mx > mrun[m] + 8.f;
      if (__any(grow)) {  // rescale path (rare after warmup)
        const float nm = fmaxf(mrun[m], mx);
        const float alpha = __expf(mrun[m] - nm);
        mrun[m] = nm;
        lrun[m] *= alpha;
#pragma unroll
        for (int r = 0; r < 4; ++r) {
          const float a_o = __shfl(alpha, 4 * (lane >> 4) + r, 64);
#pragma unroll
          for (int n = 0; n < 4; ++n) o[m][n][r] *= a_o;
        }
      }

      // P = exp(st - mrun), packed b64 into LDS; row sum
      float rs = 0.f;
#pragma unroll
      for (int kc = 0; kc < 4; ++kc) {
        bf16x4 pk;
#pragma unroll
        for (int r = 0; r < 4; ++r) {
          const float p = __expf(st[m][kc][r] - mrun[m]);
          rs += p;
          pk[r] = (__bf16)p;
        }
        *reinterpret_cast<bf16x4*>(&Ps[w][m * 16 + lr][kc * 16 + 4 * lb]) = pk;
      }
      rs += __shfl_xor(rs, 16, 64);
      rs += __shfl_xor(rs, 32, 64);
      lrun[m] += rs;
    }

    asm volatile("s_waitcnt lgkmcnt(0)" ::: "memory");
    __builtin_amdgcn_sched_barrier(0);

    bf16x8 pa[2][2];
#pragma unroll
    for (int m = 0; m < 2; ++m)
#pragma unroll
      for (int ks = 0; ks < 2; ++ks)
        pa[m][ks] = *reinterpret_cast<const bf16x8*>(&Ps[w][m * 16 + lr][ks * 32 + lb * 8]);

    __builtin_amdgcn_s_setprio(1);
#pragma unroll
    for (int m = 0; m < 2; ++m)
#pragma unroll
      for (int n = 0; n < 4; ++n) {
        o[m][n] = __builtin_amdgcn_mfma_f32_16x16x32_bf16(pa[m][0], vf[n][0], o[m][n], 0, 0, 0);
        o[m][n] = __builtin_amdgcn_mfma_f32_16x16x32_bf16(pa[m][1], vf[n][1], o[m][n], 0, 0, 0);
      }
    __builtin_amdgcn_s_setprio(0);
  }

  // epilogue: normalize (lrun lives at q=lr; o at q=4lb+r -> shuffle), write
#pragma unroll
  for (int m = 0; m < 2; ++m)
#pragma unroll
    for (int r = 0; r < 4; ++r) {
      const float ln = __shfl(lrun[m], 4 * (lane >> 4) + r, 64);
      const float inv = 1.f / ln;
      const int q = q0 + m * 16 + 4 * lb + r;
#pragma unroll
      for (int n = 0; n < 4; ++n)
        AO[((size_t)(bb * S + q)) * D + h * DK + n * 16 + lr] = (__bf16)(o[m][n][r] * inv);
    }
}

// ---------------------------------------------------------------------------
// Kernel 3: out = attn_out @ w_o^T, f32 output.
// ---------------------------------------------------------------------------
__global__ __launch_bounds__(256) void out_gemm(const __bf16* __restrict__ AOp,
                                                const float* __restrict__ W,
                                                float* __restrict__ Out) {
  __shared__ __bf16 As[128][40];
  __shared__ __bf16 Bs[128][40];
  const int tid = threadIdx.x;
  const int lane = tid & 63;
  const int wid = tid >> 6;
  const int wr = wid >> 1, wc = wid & 1;
  const int lr = lane & 15, lb = lane >> 4;
  const int m0 = blockIdx.x * 128, n0 = blockIdx.y * 128;
  const int srow = tid >> 3, scol = (tid & 7) << 2;
  const int arow = tid >> 2, acol = (tid & 3) << 3;

  f32x4 acc[4][4];
#pragma unroll
  for (int i = 0; i < 4; ++i)
#pragma unroll
    for (int j = 0; j < 4; ++j) acc[i][j] = f32x4{0.f, 0.f, 0.f, 0.f};

  for (int k0 = 0; k0 < D; k0 += 32) {
#pragma unroll
    for (int p = 0; p < 2; ++p) {
      const int r = p * 64 + arow;
      bf16x8 av = *reinterpret_cast<const bf16x8*>(&AOp[(size_t)(m0 + r) * D + k0 + acol]);
      *reinterpret_cast<bf16x8*>(&As[r][acol]) = av;
    }
#pragma unroll
    for (int p = 0; p < 4; ++p) {
      const int r = p * 32 + srow;
      float4 w = *reinterpret_cast<const float4*>(&W[(size_t)(n0 + r) * D + k0 + scol]);
      bf16x4 wb = {(__bf16)w.x, (__bf16)w.y, (__bf16)w.z, (__bf16)w.w};
      *reinterpret_cast<bf16x4*>(&Bs[r][scol]) = wb;
    }
    __syncthreads();
    bf16x8 af[4], bfr[4];
#pragma unroll
    for (int m = 0; m < 4; ++m)
      af[m] = *reinterpret_cast<const bf16x8*>(&As[wr * 64 + m * 16 + lr][lb * 8]);
#pragma unroll
    for (int n = 0; n < 4; ++n)
      bfr[n] = *reinterpret_cast<const bf16x8*>(&Bs[wc * 64 + n * 16 + lr][lb * 8]);
#pragma unroll
    for (int m = 0; m < 4; ++m)
#pragma unroll
      for (int n = 0; n < 4; ++n)
        acc[m][n] = __builtin_amdgcn_mfma_f32_16x16x32_bf16(af[m], bfr[n], acc[m][n], 0, 0, 0);
    __syncthreads();
  }

#pragma unroll
  for (int m = 0; m < 4; ++m)
#pragma unroll
    for (int n = 0; n < 4; ++n)
#pragma unroll
      for (int r = 0; r < 4; ++r)
        Out[(size_t)(m0 + wr * 64 + m * 16 + lb * 4 + r) * D + n0 + wc * 64 + n * 16 + lr] =
            acc[m][n][r];
}

// ---------------------------------------------------------------------------
extern "C" void kernel_launch(void* const* d_in, const int* in_sizes, int n_in,
                              void* d_out, int out_size, void* d_ws, size_t ws_size,
                              hipStream_t stream) {
  (void)in_sizes; (void)n_in; (void)out_size; (void)ws_size;
  const float* x = (const float*)d_in[0];
  // d_in[1] = causal mask — recomputed analytically, not read
  const float* w_qkv = (const float*)d_in[2];
  const float* b_qkv = (const float*)d_in[3];
  const float* w_o = (const float*)d_in[4];
  float* out = (float*)d_out;

  const size_t qkv_elems = (size_t)B * H * S * DK;  // 8,388,608
  __bf16* Qb = (__bf16*)d_ws;
  __bf16* Kb = Qb + qkv_elems;
  __bf16* VTb = Kb + qkv_elems;
  __bf16* AO = VTb + qkv_elems;  // 64 MB of workspace

  qkv_gemm<<<dim3(64, 24), 256, 0, stream>>>(x, w_qkv, b_qkv, Qb, Kb, VTb);
  attn_fwd<<<dim3((S / 128) * (B * H)), 256, 0, stream>>>(Qb, Kb, VTb, AO);
  out_gemm<<<dim3(64, 8), 256, 0, stream>>>(AO, w_o, out);
}

// Round 5
// 272.053 us; speedup vs baseline: 1.5915x; 1.2529x over previous
//
#include <hip/hip_runtime.h>
#include <hip/hip_bf16.h>

typedef __attribute__((ext_vector_type(8))) __bf16 bf16x8;
typedef __attribute__((ext_vector_type(4))) __bf16 bf16x4;
typedef __attribute__((ext_vector_type(4))) float f32x4;

constexpr int B = 4, S = 2048, D = 1024, H = 16, DK = 64;

// ---------------------------------------------------------------------------
// Kernel 1: qkv = x @ w_qkv^T + b_qkv ; scatter to Q [B,H,S,DK] (scaled by
// log2(e)/sqrt(DK) so attention softmax runs in exp2 domain), K [B,H,S,DK],
// V^T [B,H,DK,S], all bf16.
// ---------------------------------------------------------------------------
__global__ __launch_bounds__(256) void qkv_gemm(const float* __restrict__ X,
                                                const float* __restrict__ W,
                                                const float* __restrict__ bias,
                                                __bf16* __restrict__ Qb,
                                                __bf16* __restrict__ Kb,
                                                __bf16* __restrict__ VTb) {
  __shared__ __bf16 As[128][40];
  __shared__ __bf16 Bs[128][40];
  const int tid = threadIdx.x;
  const int lane = tid & 63;
  const int wid = tid >> 6;
  const int wr = wid >> 1, wc = wid & 1;
  const int lr = lane & 15, lb = lane >> 4;
  const int m0 = blockIdx.x * 128, n0 = blockIdx.y * 128;
  const int srow = tid >> 3;
  const int scol = (tid & 7) << 2;

  f32x4 acc[4][4];
#pragma unroll
  for (int i = 0; i < 4; ++i)
#pragma unroll
    for (int j = 0; j < 4; ++j) acc[i][j] = f32x4{0.f, 0.f, 0.f, 0.f};

  for (int k0 = 0; k0 < D; k0 += 32) {
#pragma unroll
    for (int p = 0; p < 4; ++p) {
      const int r = p * 32 + srow;
      float4 a = *reinterpret_cast<const float4*>(&X[(size_t)(m0 + r) * D + k0 + scol]);
      float4 w = *reinterpret_cast<const float4*>(&W[(size_t)(n0 + r) * D + k0 + scol]);
      bf16x4 ab = {(__bf16)a.x, (__bf16)a.y, (__bf16)a.z, (__bf16)a.w};
      bf16x4 wb = {(__bf16)w.x, (__bf16)w.y, (__bf16)w.z, (__bf16)w.w};
      *reinterpret_cast<bf16x4*>(&As[r][scol]) = ab;
      *reinterpret_cast<bf16x4*>(&Bs[r][scol]) = wb;
    }
    __syncthreads();
    bf16x8 af[4], bfr[4];
#pragma unroll
    for (int m = 0; m < 4; ++m)
      af[m] = *reinterpret_cast<const bf16x8*>(&As[wr * 64 + m * 16 + lr][lb * 8]);
#pragma unroll
    for (int n = 0; n < 4; ++n)
      bfr[n] = *reinterpret_cast<const bf16x8*>(&Bs[wc * 64 + n * 16 + lr][lb * 8]);
#pragma unroll
    for (int m = 0; m < 4; ++m)
#pragma unroll
      for (int n = 0; n < 4; ++n)
        acc[m][n] = __builtin_amdgcn_mfma_f32_16x16x32_bf16(af[m], bfr[n], acc[m][n], 0, 0, 0);
    __syncthreads();
  }

  const int seg = n0 >> 10;
#pragma unroll
  for (int m = 0; m < 4; ++m)
#pragma unroll
    for (int n = 0; n < 4; ++n) {
      const int c = n0 + wc * 64 + n * 16 + lr;
      const int cc = c & 1023;
      const int h = cc >> 6, dk = cc & 63;
      const float bv = bias[c];
#pragma unroll
      for (int r = 0; r < 4; ++r) {
        const int t = m0 + wr * 64 + m * 16 + lb * 4 + r;
        const int bb = t >> 11;
        const int s = t & 2047;
        const float v = acc[m][n][r] + bv;
        const size_t bh = (size_t)bb * H + h;
        if (seg == 0)
          Qb[(bh * S + s) * DK + dk] = (__bf16)(v * 0.180336893f);  // 0.125*log2(e)
        else if (seg == 1)
          Kb[(bh * S + s) * DK + dk] = (__bf16)v;
        else
          VTb[(bh * DK + dk) * S + s] = (__bf16)v;
      }
    }
}

// ---------------------------------------------------------------------------
// Kernel 2 (round 4 rewrite): block-cooperative causal flash attention.
// Flat grid 1024: xcd=flat&7, idx=flat>>3, bh=(idx>>4)*8+xcd (head->XCD L2
// locality), qt=15-(idx&15) (LPT heavy-first). 4 waves/block; wave w owns
// q-rows [qt*128+w*32, +32). KVBLK=64.
// K/V tiles staged ONCE per block into LDS (reg-staged, XOR-swizzled
// byte^=(row&7)<<4 on both write and read; [64][64] keeps 16B alignment,
// <=2-way conflicts). T14 pipeline: issue t+1 global loads -> compute tile t
// from LDS -> barrier -> ds_write t+1 -> barrier. Waves 0/1 skip compute on
// the block's last tile (trip-count difference) but join barriers.
// Swapped QK^T (S^T via mfma(K,Q)); softmax in exp2 domain; defer-max THR=11.
// ---------------------------------------------------------------------------
__global__ __launch_bounds__(256) void attn_fwd(const __bf16* __restrict__ Qb,
                                                const __bf16* __restrict__ Kb,
                                                const __bf16* __restrict__ VTb,
                                                __bf16* __restrict__ AO) {
  __shared__ __bf16 Kl[2][64 * 64];
  __shared__ __bf16 Vl[2][64 * 64];
  __shared__ __bf16 Ps[4][32][72];
  const int tid = threadIdx.x;
  const int lane = tid & 63;
  const int w = tid >> 6;
  const int lr = lane & 15, lb = lane >> 4;

  const int flat = blockIdx.x;
  const int xcd = flat & 7;
  const int idx = flat >> 3;
  const int bh = (idx >> 4) * 8 + xcd;
  const int qt = 15 - (idx & 15);
  const int q0 = qt * 128 + w * 32;
  const int bb = bh >> 4, h = bh & 15;

  const __bf16* Q = Qb + (size_t)bh * S * DK;
  const __bf16* K = Kb + (size_t)bh * S * DK;
  const __bf16* VT = VTb + (size_t)bh * DK * S;

  const int nt = 2 * qt + 2;             // block trip count
  const int ntw = 2 * qt + 1 + (w >> 1); // this wave's compute trip count

  // staging geometry: 256 threads stage one 64x64 bf16 tile (8KB) of each
  const int srow = tid >> 2;        // 0..63 (K: kv row, V: d row)
  const int scol = (tid & 3) * 16;  // element col (16 elems = 32B)
  const int sbyte = srow * 128 + scol * 2;
  const int sswz = (srow & 7) << 4;

  bf16x8 qf[2][2];
#pragma unroll
  for (int m = 0; m < 2; ++m)
#pragma unroll
    for (int d = 0; d < 2; ++d)
      qf[m][d] = *reinterpret_cast<const bf16x8*>(
          &Q[(size_t)(q0 + m * 16 + lr) * DK + d * 32 + lb * 8]);

  // prologue: stage tile 0 into buffer 0
  {
    const __bf16* Kg = K + (size_t)srow * DK + scol;
    bf16x8 k0 = *reinterpret_cast<const bf16x8*>(Kg);
    bf16x8 k1 = *reinterpret_cast<const bf16x8*>(Kg + 8);
    const __bf16* Vg = VT + (size_t)srow * S + scol;
    bf16x8 v0 = *reinterpret_cast<const bf16x8*>(Vg);
    bf16x8 v1 = *reinterpret_cast<const bf16x8*>(Vg + 8);
    char* kd = (char*)&Kl[0][0];
    char* vd = (char*)&Vl[0][0];
    *reinterpret_cast<bf16x8*>(kd + (sbyte ^ sswz)) = k0;
    *reinterpret_cast<bf16x8*>(kd + ((sbyte + 16) ^ sswz)) = k1;
    *reinterpret_cast<bf16x8*>(vd + (sbyte ^ sswz)) = v0;
    *reinterpret_cast<bf16x8*>(vd + ((sbyte + 16) ^ sswz)) = v1;
  }
  __syncthreads();

  f32x4 o[2][4];
#pragma unroll
  for (int m = 0; m < 2; ++m)
#pragma unroll
    for (int n = 0; n < 4; ++n) o[m][n] = f32x4{0.f, 0.f, 0.f, 0.f};
  float mrun[2], lrun[2];  // per q = lr, exp2 domain
#pragma unroll
  for (int m = 0; m < 2; ++m) {
    mrun[m] = -1e30f;
    lrun[m] = 0.f;
  }

  for (int t = 0; t < nt; ++t) {
    const int cur = t & 1;
    const int kv0 = t * 64;
    const bool have_next = (t + 1 < nt);
    bf16x8 gk0, gk1, gv0, gv1;
    if (have_next) {  // issue next-tile loads early (latency hides under compute)
      const __bf16* Kg = K + ((size_t)(kv0 + 64) + srow) * DK + scol;
      gk0 = *reinterpret_cast<const bf16x8*>(Kg);
      gk1 = *reinterpret_cast<const bf16x8*>(Kg + 8);
      const __bf16* Vg = VT + (size_t)srow * S + (kv0 + 64) + scol;
      gv0 = *reinterpret_cast<const bf16x8*>(Vg);
      gv1 = *reinterpret_cast<const bf16x8*>(Vg + 8);
    }

    if (t < ntw) {
      const char* kbase = (const char*)&Kl[cur][0];
      const char* vbase = (const char*)&Vl[cur][0];
      const int rsw = (lr & 7) << 4;
      bf16x8 kf[4][2];
#pragma unroll
      for (int kc = 0; kc < 4; ++kc)
#pragma unroll
        for (int d = 0; d < 2; ++d)
          kf[kc][d] = *reinterpret_cast<const bf16x8*>(
              kbase + (kc * 16 + lr) * 128 + ((d * 64 + lb * 16) ^ rsw));

      // swapped QK^T: st[m][kc][r] = S^T[k=kv0+kc*16+4lb+r][q=q0+m*16+lr]
      f32x4 st[2][4];
      __builtin_amdgcn_s_setprio(1);
#pragma unroll
      for (int m = 0; m < 2; ++m)
#pragma unroll
        for (int kc = 0; kc < 4; ++kc) {
          f32x4 z = f32x4{0.f, 0.f, 0.f, 0.f};
          z = __builtin_amdgcn_mfma_f32_16x16x32_bf16(kf[kc][0], qf[m][0], z, 0, 0, 0);
          z = __builtin_amdgcn_mfma_f32_16x16x32_bf16(kf[kc][1], qf[m][1], z, 0, 0, 0);
          st[m][kc] = z;
        }
      __builtin_amdgcn_s_setprio(0);

      if (t == ntw - 1) {  // diagonal tile: mask k > q
#pragma unroll
        for (int m = 0; m < 2; ++m) {
          const int qg = q0 + m * 16 + lr;
#pragma unroll
          for (int kc = 0; kc < 4; ++kc)
#pragma unroll
            for (int r = 0; r < 4; ++r) {
              const int kg = kv0 + kc * 16 + 4 * lb + r;
              if (kg > qg) st[m][kc][r] = -1e30f;
            }
        }
      }

#pragma unroll
      for (int m = 0; m < 2; ++m) {
        float mx = st[m][0][0];
#pragma unroll
        for (int kc = 0; kc < 4; ++kc)
#pragma unroll
          for (int r = 0; r < 4; ++r) mx = fmaxf(mx, st[m][kc][r]);
        mx = fmaxf(mx, __shfl_xor(mx, 16, 64));
        mx = fmaxf(mx, __shfl_xor(mx, 32, 64));

        if (__any(mx > mrun[m] + 11.f)) {  // defer-max (exp2 domain)
          const float nm = fmaxf(mrun[m], mx);
          const float alpha = exp2f(mrun[m] - nm);
          mrun[m] = nm;
          lrun[m] *= alpha;
#pragma unroll
          for (int r = 0; r < 4; ++r) {
            const float ao = __shfl(alpha, 4 * lb + r, 64);
#pragma unroll
            for (int n = 0; n < 4; ++n) o[m][n][r] *= ao;
          }
        }

        float rs = 0.f;
#pragma unroll
        for (int kc = 0; kc < 4; ++kc) {
          bf16x4 pk;
#pragma unroll
          for (int r = 0; r < 4; ++r) {
            const float p = exp2f(st[m][kc][r] - mrun[m]);
            rs += p;
            pk[r] = (__bf16)p;
          }
          *reinterpret_cast<bf16x4*>(&Ps[w][m * 16 + lr][kc * 16 + 4 * lb]) = pk;
        }
        rs += __shfl_xor(rs, 16, 64);
        rs += __shfl_xor(rs, 32, 64);
        lrun[m] += rs;
      }

      asm volatile("s_waitcnt lgkmcnt(0)" ::: "memory");
      __builtin_amdgcn_sched_barrier(0);

      bf16x8 pa[2][2];
#pragma unroll
      for (int m = 0; m < 2; ++m)
#pragma unroll
        for (int ks = 0; ks < 2; ++ks)
          pa[m][ks] = *reinterpret_cast<const bf16x8*>(&Ps[w][m * 16 + lr][ks * 32 + lb * 8]);
      bf16x8 vf[4][2];
#pragma unroll
      for (int n = 0; n < 4; ++n)
#pragma unroll
        for (int ks = 0; ks < 2; ++ks)
          vf[n][ks] = *reinterpret_cast<const bf16x8*>(
              vbase + (n * 16 + lr) * 128 + ((ks * 64 + lb * 16) ^ rsw));

      __builtin_amdgcn_s_setprio(1);
#pragma unroll
      for (int m = 0; m < 2; ++m)
#pragma unroll
        for (int n = 0; n < 4; ++n) {
          o[m][n] = __builtin_amdgcn_mfma_f32_16x16x32_bf16(pa[m][0], vf[n][0], o[m][n], 0, 0, 0);
          o[m][n] = __builtin_amdgcn_mfma_f32_16x16x32_bf16(pa[m][1], vf[n][1], o[m][n], 0, 0, 0);
        }
      __builtin_amdgcn_s_setprio(0);
    }

    __syncthreads();  // all waves done reading buf[cur^1] (finished last iter)
    if (have_next) {
      char* kd = (char*)&Kl[cur ^ 1][0];
      char* vd = (char*)&Vl[cur ^ 1][0];
      *reinterpret_cast<bf16x8*>(kd + (sbyte ^ sswz)) = gk0;
      *reinterpret_cast<bf16x8*>(kd + ((sbyte + 16) ^ sswz)) = gk1;
      *reinterpret_cast<bf16x8*>(vd + (sbyte ^ sswz)) = gv0;
      *reinterpret_cast<bf16x8*>(vd + ((sbyte + 16) ^ sswz)) = gv1;
    }
    __syncthreads();  // staged tile visible before next compute
  }

  // epilogue: normalize (lrun at q=lr; o rows at q=4lb+r -> shuffle), write
#pragma unroll
  for (int m = 0; m < 2; ++m)
#pragma unroll
    for (int r = 0; r < 4; ++r) {
      const float ln = __shfl(lrun[m], 4 * lb + r, 64);
      const float inv = 1.f / ln;
      const int q = q0 + m * 16 + 4 * lb + r;
#pragma unroll
      for (int n = 0; n < 4; ++n)
        AO[((size_t)(bb * S + q)) * D + h * DK + n * 16 + lr] = (__bf16)(o[m][n][r] * inv);
    }
}

// ---------------------------------------------------------------------------
// Kernel 3: out = attn_out @ w_o^T, f32 output.
// ---------------------------------------------------------------------------
__global__ __launch_bounds__(256) void out_gemm(const __bf16* __restrict__ AOp,
                                                const float* __restrict__ W,
                                                float* __restrict__ Out) {
  __shared__ __bf16 As[128][40];
  __shared__ __bf16 Bs[128][40];
  const int tid = threadIdx.x;
  const int lane = tid & 63;
  const int wid = tid >> 6;
  const int wr = wid >> 1, wc = wid & 1;
  const int lr = lane & 15, lb = lane >> 4;
  const int m0 = blockIdx.x * 128, n0 = blockIdx.y * 128;
  const int srow = tid >> 3, scol = (tid & 7) << 2;
  const int arow = tid >> 2, acol = (tid & 3) << 3;

  f32x4 acc[4][4];
#pragma unroll
  for (int i = 0; i < 4; ++i)
#pragma unroll
    for (int j = 0; j < 4; ++j) acc[i][j] = f32x4{0.f, 0.f, 0.f, 0.f};

  for (int k0 = 0; k0 < D; k0 += 32) {
#pragma unroll
    for (int p = 0; p < 2; ++p) {
      const int r = p * 64 + arow;
      bf16x8 av = *reinterpret_cast<const bf16x8*>(&AOp[(size_t)(m0 + r) * D + k0 + acol]);
      *reinterpret_cast<bf16x8*>(&As[r][acol]) = av;
    }
#pragma unroll
    for (int p = 0; p < 4; ++p) {
      const int r = p * 32 + srow;
      float4 w = *reinterpret_cast<const float4*>(&W[(size_t)(n0 + r) * D + k0 + scol]);
      bf16x4 wb = {(__bf16)w.x, (__bf16)w.y, (__bf16)w.z, (__bf16)w.w};
      *reinterpret_cast<bf16x4*>(&Bs[r][scol]) = wb;
    }
    __syncthreads();
    bf16x8 af[4], bfr[4];
#pragma unroll
    for (int m = 0; m < 4; ++m)
      af[m] = *reinterpret_cast<const bf16x8*>(&As[wr * 64 + m * 16 + lr][lb * 8]);
#pragma unroll
    for (int n = 0; n < 4; ++n)
      bfr[n] = *reinterpret_cast<const bf16x8*>(&Bs[wc * 64 + n * 16 + lr][lb * 8]);
#pragma unroll
    for (int m = 0; m < 4; ++m)
#pragma unroll
      for (int n = 0; n < 4; ++n)
        acc[m][n] = __builtin_amdgcn_mfma_f32_16x16x32_bf16(af[m], bfr[n], acc[m][n], 0, 0, 0);
    __syncthreads();
  }

#pragma unroll
  for (int m = 0; m < 4; ++m)
#pragma unroll
    for (int n = 0; n < 4; ++n)
#pragma unroll
      for (int r = 0; r < 4; ++r)
        Out[(size_t)(m0 + wr * 64 + m * 16 + lb * 4 + r) * D + n0 + wc * 64 + n * 16 + lr] =
            acc[m][n][r];
}

// ---------------------------------------------------------------------------
extern "C" void kernel_launch(void* const* d_in, const int* in_sizes, int n_in,
                              void* d_out, int out_size, void* d_ws, size_t ws_size,
                              hipStream_t stream) {
  (void)in_sizes; (void)n_in; (void)out_size; (void)ws_size;
  const float* x = (const float*)d_in[0];
  // d_in[1] = causal mask — recomputed analytically, not read
  const float* w_qkv = (const float*)d_in[2];
  const float* b_qkv = (const float*)d_in[3];
  const float* w_o = (const float*)d_in[4];
  float* out = (float*)d_out;

  const size_t qkv_elems = (size_t)B * H * S * DK;  // 8,388,608
  __bf16* Qb = (__bf16*)d_ws;
  __bf16* Kb = Qb + qkv_elems;
  __bf16* VTb = Kb + qkv_elems;
  __bf16* AO = VTb + qkv_elems;  // 64 MB of workspace

  qkv_gemm<<<dim3(64, 24), 256, 0, stream>>>(x, w_qkv, b_qkv, Qb, Kb, VTb);
  attn_fwd<<<dim3((S / 128) * (B * H)), 256, 0, stream>>>(Qb, Kb, VTb, AO);
  out_gemm<<<dim3(64, 8), 256, 0, stream>>>(AO, w_o, out);
}

// Round 6
// 242.379 us; speedup vs baseline: 1.7863x; 1.1224x over previous
//
#include <hip/hip_runtime.h>
#include <hip/hip_bf16.h>

typedef __attribute__((ext_vector_type(8))) __bf16 bf16x8;
typedef __attribute__((ext_vector_type(4))) __bf16 bf16x4;
typedef __attribute__((ext_vector_type(4))) float f32x4;

constexpr int B = 4, S = 2048, D = 1024, H = 16, DK = 64;

#define GLOAD16(gp, lp)                                                              \
  __builtin_amdgcn_global_load_lds((const __attribute__((address_space(1))) void*)(gp), \
                                   (__attribute__((address_space(3))) void*)(lp), 16, 0, 0)

// ---------------------------------------------------------------------------
// Kernel 0: one-shot f32 -> bf16 conversion of X, w_qkv, w_o into workspace.
// ---------------------------------------------------------------------------
__global__ __launch_bounds__(256) void convert_bf16(const float* __restrict__ X,
                                                    const float* __restrict__ Wqkv,
                                                    const float* __restrict__ Wo,
                                                    __bf16* __restrict__ Xb,
                                                    __bf16* __restrict__ Wqkvb,
                                                    __bf16* __restrict__ Wob) {
  const int NX = B * S * D;      // 8,388,608
  const int NW = 3 * D * D;      // 3,145,728
  const int NO = D * D;          // 1,048,576
  const int total8 = (NX + NW + NO) / 8;
  for (int i = blockIdx.x * blockDim.x + threadIdx.x; i < total8;
       i += gridDim.x * blockDim.x) {
    const int e = i * 8;
    const float* src;
    __bf16* dst;
    int off;
    if (e < NX) {
      src = X; dst = Xb; off = e;
    } else if (e < NX + NW) {
      src = Wqkv; dst = Wqkvb; off = e - NX;
    } else {
      src = Wo; dst = Wob; off = e - NX - NW;
    }
    float4 a = *reinterpret_cast<const float4*>(src + off);
    float4 b = *reinterpret_cast<const float4*>(src + off + 4);
    bf16x8 v = {(__bf16)a.x, (__bf16)a.y, (__bf16)a.z, (__bf16)a.w,
                (__bf16)b.x, (__bf16)b.y, (__bf16)b.z, (__bf16)b.w};
    *reinterpret_cast<bf16x8*>(dst + off) = v;
  }
}

// ---------------------------------------------------------------------------
// Kernel 1 (round 5 rewrite, m97 structure): qkv = Xb @ Wqkvb^T + b ; scatter
// to Q (scaled by 0.125*log2(e)), K, V^T, all bf16.
// 128x128 tile, BK=64, 4 waves 2x2. Staging via global_load_lds width-16 into
// linear [128][64] LDS; XOR swizzle byte^=(row&7)<<4 applied by pre-swizzling
// the per-lane GLOBAL source column (rule #21) and on the ds_read side.
// Per K-step: 8 gload_lds + 16 ds_read_b128 + 32 MFMA.
// ---------------------------------------------------------------------------
__global__ __launch_bounds__(256) void qkv_gemm(const __bf16* __restrict__ Xb,
                                                const __bf16* __restrict__ Wb,
                                                const float* __restrict__ bias,
                                                __bf16* __restrict__ Qb,
                                                __bf16* __restrict__ Kb,
                                                __bf16* __restrict__ VTb) {
  __shared__ __bf16 As[128 * 64];
  __shared__ __bf16 Bs[128 * 64];
  const int tid = threadIdx.x;
  const int lane = tid & 63;
  const int w = tid >> 6;
  const int wr = w >> 1, wc = w & 1;
  const int lr = lane & 15, lb = lane >> 4;
  const int m0 = blockIdx.x * 128, n0 = blockIdx.y * 128;

  // staging geometry: round rnd covers LDS 16B-chunks i = rnd*256 + tid
  int srow[4], sgcol[4];
#pragma unroll
  for (int rnd = 0; rnd < 4; ++rnd) {
    const int i = rnd * 256 + tid;
    srow[rnd] = i >> 3;
    sgcol[rnd] = ((i & 7) ^ (srow[rnd] & 7)) << 3;  // pre-swizzled source col
  }

  f32x4 acc[4][4];
#pragma unroll
  for (int i = 0; i < 4; ++i)
#pragma unroll
    for (int j = 0; j < 4; ++j) acc[i][j] = f32x4{0.f, 0.f, 0.f, 0.f};

  for (int k0 = 0; k0 < D; k0 += 64) {
#pragma unroll
    for (int rnd = 0; rnd < 4; ++rnd) {
      GLOAD16(&Xb[(size_t)(m0 + srow[rnd]) * D + k0 + sgcol[rnd]],
              (char*)As + rnd * 4096 + w * 1024);
      GLOAD16(&Wb[(size_t)(n0 + srow[rnd]) * D + k0 + sgcol[rnd]],
              (char*)Bs + rnd * 4096 + w * 1024);
    }
    __syncthreads();  // drains vmcnt (compiler emits the waitcnt)

    bf16x8 af[4][2], bfr[4][2];
#pragma unroll
    for (int m = 0; m < 4; ++m) {
      const int row = wr * 64 + m * 16 + lr;
#pragma unroll
      for (int ks = 0; ks < 2; ++ks)
        af[m][ks] = *reinterpret_cast<const bf16x8*>(
            (const char*)As + row * 128 + (((ks * 32 + lb * 8) << 1) ^ ((row & 7) << 4)));
    }
#pragma unroll
    for (int n = 0; n < 4; ++n) {
      const int row = wc * 64 + n * 16 + lr;
#pragma unroll
      for (int ks = 0; ks < 2; ++ks)
        bfr[n][ks] = *reinterpret_cast<const bf16x8*>(
            (const char*)Bs + row * 128 + (((ks * 32 + lb * 8) << 1) ^ ((row & 7) << 4)));
    }
#pragma unroll
    for (int m = 0; m < 4; ++m)
#pragma unroll
      for (int n = 0; n < 4; ++n) {
        acc[m][n] = __builtin_amdgcn_mfma_f32_16x16x32_bf16(af[m][0], bfr[n][0], acc[m][n], 0, 0, 0);
        acc[m][n] = __builtin_amdgcn_mfma_f32_16x16x32_bf16(af[m][1], bfr[n][1], acc[m][n], 0, 0, 0);
      }
    __syncthreads();
  }

  const int seg = n0 >> 10;  // 0:Q 1:K 2:V
#pragma unroll
  for (int m = 0; m < 4; ++m)
#pragma unroll
    for (int n = 0; n < 4; ++n) {
      const int c = n0 + wc * 64 + n * 16 + lr;
      const int cc = c & 1023;
      const int h = cc >> 6, dk = cc & 63;
      const float bv = bias[c];
#pragma unroll
      for (int r = 0; r < 4; ++r) {
        const int t = m0 + wr * 64 + m * 16 + lb * 4 + r;
        const int bb = t >> 11;
        const int s = t & 2047;
        const float v = acc[m][n][r] + bv;
        const size_t bh = (size_t)bb * H + h;
        if (seg == 0)
          Qb[(bh * S + s) * DK + dk] = (__bf16)(v * 0.180336893f);  // 0.125*log2(e)
        else if (seg == 1)
          Kb[(bh * S + s) * DK + dk] = (__bf16)v;
        else
          VTb[(bh * DK + dk) * S + s] = (__bf16)v;
      }
    }
}

// ---------------------------------------------------------------------------
// Kernel 2 (unchanged from round 4): block-cooperative causal flash attention.
// ---------------------------------------------------------------------------
__global__ __launch_bounds__(256) void attn_fwd(const __bf16* __restrict__ Qb,
                                                const __bf16* __restrict__ Kb,
                                                const __bf16* __restrict__ VTb,
                                                __bf16* __restrict__ AO) {
  __shared__ __bf16 Kl[2][64 * 64];
  __shared__ __bf16 Vl[2][64 * 64];
  __shared__ __bf16 Ps[4][32][72];
  const int tid = threadIdx.x;
  const int lane = tid & 63;
  const int w = tid >> 6;
  const int lr = lane & 15, lb = lane >> 4;

  const int flat = blockIdx.x;
  const int xcd = flat & 7;
  const int idx = flat >> 3;
  const int bh = (idx >> 4) * 8 + xcd;
  const int qt = 15 - (idx & 15);
  const int q0 = qt * 128 + w * 32;
  const int bb = bh >> 4, h = bh & 15;

  const __bf16* Q = Qb + (size_t)bh * S * DK;
  const __bf16* K = Kb + (size_t)bh * S * DK;
  const __bf16* VT = VTb + (size_t)bh * DK * S;

  const int nt = 2 * qt + 2;
  const int ntw = 2 * qt + 1 + (w >> 1);

  const int srow = tid >> 2;
  const int scol = (tid & 3) * 16;
  const int sbyte = srow * 128 + scol * 2;
  const int sswz = (srow & 7) << 4;

  bf16x8 qf[2][2];
#pragma unroll
  for (int m = 0; m < 2; ++m)
#pragma unroll
    for (int d = 0; d < 2; ++d)
      qf[m][d] = *reinterpret_cast<const bf16x8*>(
          &Q[(size_t)(q0 + m * 16 + lr) * DK + d * 32 + lb * 8]);

  {
    const __bf16* Kg = K + (size_t)srow * DK + scol;
    bf16x8 k0 = *reinterpret_cast<const bf16x8*>(Kg);
    bf16x8 k1 = *reinterpret_cast<const bf16x8*>(Kg + 8);
    const __bf16* Vg = VT + (size_t)srow * S + scol;
    bf16x8 v0 = *reinterpret_cast<const bf16x8*>(Vg);
    bf16x8 v1 = *reinterpret_cast<const bf16x8*>(Vg + 8);
    char* kd = (char*)&Kl[0][0];
    char* vd = (char*)&Vl[0][0];
    *reinterpret_cast<bf16x8*>(kd + (sbyte ^ sswz)) = k0;
    *reinterpret_cast<bf16x8*>(kd + ((sbyte + 16) ^ sswz)) = k1;
    *reinterpret_cast<bf16x8*>(vd + (sbyte ^ sswz)) = v0;
    *reinterpret_cast<bf16x8*>(vd + ((sbyte + 16) ^ sswz)) = v1;
  }
  __syncthreads();

  f32x4 o[2][4];
#pragma unroll
  for (int m = 0; m < 2; ++m)
#pragma unroll
    for (int n = 0; n < 4; ++n) o[m][n] = f32x4{0.f, 0.f, 0.f, 0.f};
  float mrun[2], lrun[2];
#pragma unroll
  for (int m = 0; m < 2; ++m) {
    mrun[m] = -1e30f;
    lrun[m] = 0.f;
  }

  for (int t = 0; t < nt; ++t) {
    const int cur = t & 1;
    const int kv0 = t * 64;
    const bool have_next = (t + 1 < nt);
    bf16x8 gk0, gk1, gv0, gv1;
    if (have_next) {
      const __bf16* Kg = K + ((size_t)(kv0 + 64) + srow) * DK + scol;
      gk0 = *reinterpret_cast<const bf16x8*>(Kg);
      gk1 = *reinterpret_cast<const bf16x8*>(Kg + 8);
      const __bf16* Vg = VT + (size_t)srow * S + (kv0 + 64) + scol;
      gv0 = *reinterpret_cast<const bf16x8*>(Vg);
      gv1 = *reinterpret_cast<const bf16x8*>(Vg + 8);
    }

    if (t < ntw) {
      const char* kbase = (const char*)&Kl[cur][0];
      const char* vbase = (const char*)&Vl[cur][0];
      const int rsw = (lr & 7) << 4;
      bf16x8 kf[4][2];
#pragma unroll
      for (int kc = 0; kc < 4; ++kc)
#pragma unroll
        for (int d = 0; d < 2; ++d)
          kf[kc][d] = *reinterpret_cast<const bf16x8*>(
              kbase + (kc * 16 + lr) * 128 + ((d * 64 + lb * 16) ^ rsw));

      f32x4 st[2][4];
      __builtin_amdgcn_s_setprio(1);
#pragma unroll
      for (int m = 0; m < 2; ++m)
#pragma unroll
        for (int kc = 0; kc < 4; ++kc) {
          f32x4 z = f32x4{0.f, 0.f, 0.f, 0.f};
          z = __builtin_amdgcn_mfma_f32_16x16x32_bf16(kf[kc][0], qf[m][0], z, 0, 0, 0);
          z = __builtin_amdgcn_mfma_f32_16x16x32_bf16(kf[kc][1], qf[m][1], z, 0, 0, 0);
          st[m][kc] = z;
        }
      __builtin_amdgcn_s_setprio(0);

      if (t == ntw - 1) {
#pragma unroll
        for (int m = 0; m < 2; ++m) {
          const int qg = q0 + m * 16 + lr;
#pragma unroll
          for (int kc = 0; kc < 4; ++kc)
#pragma unroll
            for (int r = 0; r < 4; ++r) {
              const int kg = kv0 + kc * 16 + 4 * lb + r;
              if (kg > qg) st[m][kc][r] = -1e30f;
            }
        }
      }

#pragma unroll
      for (int m = 0; m < 2; ++m) {
        float mx = st[m][0][0];
#pragma unroll
        for (int kc = 0; kc < 4; ++kc)
#pragma unroll
          for (int r = 0; r < 4; ++r) mx = fmaxf(mx, st[m][kc][r]);
        mx = fmaxf(mx, __shfl_xor(mx, 16, 64));
        mx = fmaxf(mx, __shfl_xor(mx, 32, 64));

        if (__any(mx > mrun[m] + 11.f)) {
          const float nm = fmaxf(mrun[m], mx);
          const float alpha = exp2f(mrun[m] - nm);
          mrun[m] = nm;
          lrun[m] *= alpha;
#pragma unroll
          for (int r = 0; r < 4; ++r) {
            const float ao = __shfl(alpha, 4 * lb + r, 64);
#pragma unroll
            for (int n = 0; n < 4; ++n) o[m][n][r] *= ao;
          }
        }

        float rs = 0.f;
#pragma unroll
        for (int kc = 0; kc < 4; ++kc) {
          bf16x4 pk;
#pragma unroll
          for (int r = 0; r < 4; ++r) {
            const float p = exp2f(st[m][kc][r] - mrun[m]);
            rs += p;
            pk[r] = (__bf16)p;
          }
          *reinterpret_cast<bf16x4*>(&Ps[w][m * 16 + lr][kc * 16 + 4 * lb]) = pk;
        }
        rs += __shfl_xor(rs, 16, 64);
        rs += __shfl_xor(rs, 32, 64);
        lrun[m] += rs;
      }

      asm volatile("s_waitcnt lgkmcnt(0)" ::: "memory");
      __builtin_amdgcn_sched_barrier(0);

      bf16x8 pa[2][2];
#pragma unroll
      for (int m = 0; m < 2; ++m)
#pragma unroll
        for (int ks = 0; ks < 2; ++ks)
          pa[m][ks] = *reinterpret_cast<const bf16x8*>(&Ps[w][m * 16 + lr][ks * 32 + lb * 8]);
      bf16x8 vf[4][2];
#pragma unroll
      for (int n = 0; n < 4; ++n)
#pragma unroll
        for (int ks = 0; ks < 2; ++ks)
          vf[n][ks] = *reinterpret_cast<const bf16x8*>(
              vbase + (n * 16 + lr) * 128 + ((ks * 64 + lb * 16) ^ rsw));

      __builtin_amdgcn_s_setprio(1);
#pragma unroll
      for (int m = 0; m < 2; ++m)
#pragma unroll
        for (int n = 0; n < 4; ++n) {
          o[m][n] = __builtin_amdgcn_mfma_f32_16x16x32_bf16(pa[m][0], vf[n][0], o[m][n], 0, 0, 0);
          o[m][n] = __builtin_amdgcn_mfma_f32_16x16x32_bf16(pa[m][1], vf[n][1], o[m][n], 0, 0, 0);
        }
      __builtin_amdgcn_s_setprio(0);
    }

    __syncthreads();
    if (have_next) {
      char* kd = (char*)&Kl[cur ^ 1][0];
      char* vd = (char*)&Vl[cur ^ 1][0];
      *reinterpret_cast<bf16x8*>(kd + (sbyte ^ sswz)) = gk0;
      *reinterpret_cast<bf16x8*>(kd + ((sbyte + 16) ^ sswz)) = gk1;
      *reinterpret_cast<bf16x8*>(vd + (sbyte ^ sswz)) = gv0;
      *reinterpret_cast<bf16x8*>(vd + ((sbyte + 16) ^ sswz)) = gv1;
    }
    __syncthreads();
  }

#pragma unroll
  for (int m = 0; m < 2; ++m)
#pragma unroll
    for (int r = 0; r < 4; ++r) {
      const float ln = __shfl(lrun[m], 4 * lb + r, 64);
      const float inv = 1.f / ln;
      const int q = q0 + m * 16 + 4 * lb + r;
#pragma unroll
      for (int n = 0; n < 4; ++n)
        AO[((size_t)(bb * S + q)) * D + h * DK + n * 16 + lr] = (__bf16)(o[m][n][r] * inv);
    }
}

// ---------------------------------------------------------------------------
// Kernel 3 (round 5 rewrite, m97 structure): out = AO @ Wob^T, f32 output.
// ---------------------------------------------------------------------------
__global__ __launch_bounds__(256) void out_gemm(const __bf16* __restrict__ AOp,
                                                const __bf16* __restrict__ Wb,
                                                float* __restrict__ Out) {
  __shared__ __bf16 As[128 * 64];
  __shared__ __bf16 Bs[128 * 64];
  const int tid = threadIdx.x;
  const int lane = tid & 63;
  const int w = tid >> 6;
  const int wr = w >> 1, wc = w & 1;
  const int lr = lane & 15, lb = lane >> 4;
  const int m0 = blockIdx.x * 128, n0 = blockIdx.y * 128;

  int srow[4], sgcol[4];
#pragma unroll
  for (int rnd = 0; rnd < 4; ++rnd) {
    const int i = rnd * 256 + tid;
    srow[rnd] = i >> 3;
    sgcol[rnd] = ((i & 7) ^ (srow[rnd] & 7)) << 3;
  }

  f32x4 acc[4][4];
#pragma unroll
  for (int i = 0; i < 4; ++i)
#pragma unroll
    for (int j = 0; j < 4; ++j) acc[i][j] = f32x4{0.f, 0.f, 0.f, 0.f};

  for (int k0 = 0; k0 < D; k0 += 64) {
#pragma unroll
    for (int rnd = 0; rnd < 4; ++rnd) {
      GLOAD16(&AOp[(size_t)(m0 + srow[rnd]) * D + k0 + sgcol[rnd]],
              (char*)As + rnd * 4096 + w * 1024);
      GLOAD16(&Wb[(size_t)(n0 + srow[rnd]) * D + k0 + sgcol[rnd]],
              (char*)Bs + rnd * 4096 + w * 1024);
    }
    __syncthreads();

    bf16x8 af[4][2], bfr[4][2];
#pragma unroll
    for (int m = 0; m < 4; ++m) {
      const int row = wr * 64 + m * 16 + lr;
#pragma unroll
      for (int ks = 0; ks < 2; ++ks)
        af[m][ks] = *reinterpret_cast<const bf16x8*>(
            (const char*)As + row * 128 + (((ks * 32 + lb * 8) << 1) ^ ((row & 7) << 4)));
    }
#pragma unroll
    for (int n = 0; n < 4; ++n) {
      const int row = wc * 64 + n * 16 + lr;
#pragma unroll
      for (int ks = 0; ks < 2; ++ks)
        bfr[n][ks] = *reinterpret_cast<const bf16x8*>(
            (const char*)Bs + row * 128 + (((ks * 32 + lb * 8) << 1) ^ ((row & 7) << 4)));
    }
#pragma unroll
    for (int m = 0; m < 4; ++m)
#pragma unroll
      for (int n = 0; n < 4; ++n) {
        acc[m][n] = __builtin_amdgcn_mfma_f32_16x16x32_bf16(af[m][0], bfr[n][0], acc[m][n], 0, 0, 0);
        acc[m][n] = __builtin_amdgcn_mfma_f32_16x16x32_bf16(af[m][1], bfr[n][1], acc[m][n], 0, 0, 0);
      }
    __syncthreads();
  }

#pragma unroll
  for (int m = 0; m < 4; ++m)
#pragma unroll
    for (int n = 0; n < 4; ++n)
#pragma unroll
      for (int r = 0; r < 4; ++r)
        Out[(size_t)(m0 + wr * 64 + m * 16 + lb * 4 + r) * D + n0 + wc * 64 + n * 16 + lr] =
            acc[m][n][r];
}

// ---------------------------------------------------------------------------
extern "C" void kernel_launch(void* const* d_in, const int* in_sizes, int n_in,
                              void* d_out, int out_size, void* d_ws, size_t ws_size,
                              hipStream_t stream) {
  (void)in_sizes; (void)n_in; (void)out_size; (void)ws_size;
  const float* x = (const float*)d_in[0];
  // d_in[1] = causal mask — recomputed analytically, not read
  const float* w_qkv = (const float*)d_in[2];
  const float* b_qkv = (const float*)d_in[3];
  const float* w_o = (const float*)d_in[4];
  float* out = (float*)d_out;

  const size_t qkv_elems = (size_t)B * H * S * DK;  // 8,388,608 (= B*S*D)
  __bf16* Qb = (__bf16*)d_ws;
  __bf16* Kb = Qb + qkv_elems;
  __bf16* VTb = Kb + qkv_elems;
  __bf16* AO = VTb + qkv_elems;
  __bf16* Xb = AO + qkv_elems;
  __bf16* Wqkvb = Xb + (size_t)B * S * D;
  __bf16* Wob = Wqkvb + (size_t)3 * D * D;  // total ~92 MB of workspace

  convert_bf16<<<2048, 256, 0, stream>>>(x, w_qkv, w_o, Xb, Wqkvb, Wob);
  qkv_gemm<<<dim3(64, 24), 256, 0, stream>>>(Xb, Wqkvb, b_qkv, Qb, Kb, VTb);
  attn_fwd<<<dim3((S / 128) * (B * H)), 256, 0, stream>>>(Qb, Kb, VTb, AO);
  out_gemm<<<dim3(64, 8), 256, 0, stream>>>(AO, Wob, out);
}